// Round 1
// baseline (757.667 us; speedup 1.0000x reference)
//
#include <hip/hip_runtime.h>
#include <hip/hip_bf16.h>

// adLIF: Wx = x @ W^T (fp32 FMA GEMM, strictly sequential-K accumulation to
// mirror BLAS bit-for-bit), then sequential LIF scan over T with rounding-exact
// fp32 ops. Input dtype (fp32 vs bf16) detected ON DEVICE from x's bit pattern.
// r11 GEMM: double-buffered LDS (33.8 KB), ONE barrier per 16-k tile; ds_writes
//   of tile t+1 overlap FMA of tile t. Per-element k-order unchanged -> bit-exact.
//   C store now cached (NOT nontemporal) so Wx stays in L3 for the scan.
// r11 scan: theory = per-t store-register WAR serialized every timestep at
//   ~1000 cyc (213 us measured). Store DATA regs rotate 2 chunks deep
//   (sdat[2][8]), store ADDRESS regs are a 4-deep pointer ring (pst[4][8])
//   recomputed 2 phases after last use (WAR distance ~48 vmem ops <= 63 cap).
//   Stores issued as a group after each chunk's compute; load ring unchanged.

#define M_SZ 65536  // B*T
#define H_SZ 512
#define K_SZ 512
#define B_SZ 128
#define T_SZ 512
#define LSTR 132  // LDS row stride (dwords), %32==4: staging writes conflict-free

typedef __attribute__((ext_vector_type(4))) float f32x4;

__device__ __forceinline__ bool detect_bf16(const unsigned int* __restrict__ w) {
  int c = 0;
#pragma unroll
  for (int i = 0; i < 64; ++i) {
    unsigned int e = (w[i] >> 7) & 0xffu;
    c += (e >= 115u && e <= 131u) ? 1 : 0;
  }
  return c > 32;  // bf16 exponents cluster in [115,131]; fp32 mantissa bits don't
}

template <bool ISB>
__device__ __forceinline__ f32x4 ld4t(const void* __restrict__ p, size_t off) {
  if constexpr (!ISB) {
    return *reinterpret_cast<const f32x4*>(reinterpret_cast<const float*>(p) + off);
  } else {
    uint2 v = *reinterpret_cast<const uint2*>(reinterpret_cast<const unsigned short*>(p) + off);
    f32x4 r;
    r.x = __uint_as_float((v.x & 0xffffu) << 16);
    r.y = __uint_as_float(v.x & 0xffff0000u);
    r.z = __uint_as_float((v.y & 0xffffu) << 16);
    r.w = __uint_as_float(v.y & 0xffff0000u);
    return r;
  }
}

template <bool ISB>
__device__ __forceinline__ float ld1t(const void* __restrict__ p, int i) {
  if constexpr (!ISB) return reinterpret_cast<const float*>(p)[i];
  return __uint_as_float((unsigned int)(reinterpret_cast<const unsigned short*>(p)[i]) << 16);
}

// ---------------- GEMM: C[m][n] = sum_k X[m][k]*W[n][k], fp32, k ascending ----
template <bool ISB>
__device__ __forceinline__ void gemm_body(const void* __restrict__ X,
                                          const void* __restrict__ Wm,
                                          float* __restrict__ C,
                                          float* __restrict__ As0,
                                          float* __restrict__ Bs0,
                                          float* __restrict__ As1,
                                          float* __restrict__ Bs1) {
  const int tid = threadIdx.x;
  const int r0 = tid >> 2;       // 0..63: staged row
  const int q0 = (tid & 3) * 4;  // 0,4,8,12: k-group
  const int tx = tid & 15;       // n-group
  const int ty = tid >> 4;       // m-group
  const size_t M0 = (size_t)(blockIdx.x >> 2) * 128;
  const int N0 = (blockIdx.x & 3) * 128;

  float acc[8][8];
#pragma unroll
  for (int i = 0; i < 8; ++i)
#pragma unroll
    for (int j = 0; j < 8; ++j) acc[i][j] = 0.0f;

  const size_t aoff0 = (M0 + r0) * K_SZ + q0;
  const size_t aoff1 = (M0 + r0 + 64) * K_SZ + q0;
  const size_t boff0 = (size_t)(N0 + r0) * K_SZ + q0;
  const size_t boff1 = (size_t)(N0 + r0 + 64) * K_SZ + q0;

  f32x4 pa0, pa1, pb0, pb1;  // single reg set: stage consumes, then prefetch refills

  auto prefetch = [&](int kk) {
    pa0 = ld4t<ISB>(X, aoff0 + kk);
    pa1 = ld4t<ISB>(X, aoff1 + kk);
    pb0 = ld4t<ISB>(Wm, boff0 + kk);
    pb1 = ld4t<ISB>(Wm, boff1 + kk);
  };
  auto stage = [&](float* __restrict__ As, float* __restrict__ Bs) {
    As[(q0 + 0) * LSTR + r0] = pa0.x; As[(q0 + 1) * LSTR + r0] = pa0.y;
    As[(q0 + 2) * LSTR + r0] = pa0.z; As[(q0 + 3) * LSTR + r0] = pa0.w;
    As[(q0 + 0) * LSTR + r0 + 64] = pa1.x; As[(q0 + 1) * LSTR + r0 + 64] = pa1.y;
    As[(q0 + 2) * LSTR + r0 + 64] = pa1.z; As[(q0 + 3) * LSTR + r0 + 64] = pa1.w;
    Bs[(q0 + 0) * LSTR + r0] = pb0.x; Bs[(q0 + 1) * LSTR + r0] = pb0.y;
    Bs[(q0 + 2) * LSTR + r0] = pb0.z; Bs[(q0 + 3) * LSTR + r0] = pb0.w;
    Bs[(q0 + 0) * LSTR + r0 + 64] = pb1.x; Bs[(q0 + 1) * LSTR + r0 + 64] = pb1.y;
    Bs[(q0 + 2) * LSTR + r0 + 64] = pb1.z; Bs[(q0 + 3) * LSTR + r0 + 64] = pb1.w;
  };
  auto compute = [&](const float* __restrict__ As, const float* __restrict__ Bs) {
#pragma unroll
    for (int k = 0; k < 16; ++k) {
      const f32x4 a0 = *reinterpret_cast<const f32x4*>(As + k * LSTR + ty * 4);
      const f32x4 a1 = *reinterpret_cast<const f32x4*>(As + k * LSTR + 64 + ty * 4);
      const f32x4 b0 = *reinterpret_cast<const f32x4*>(Bs + k * LSTR + tx * 4);
      const f32x4 b1 = *reinterpret_cast<const f32x4*>(Bs + k * LSTR + 64 + tx * 4);
      const float avv[8] = {a0.x, a0.y, a0.z, a0.w, a1.x, a1.y, a1.z, a1.w};
      const float bvv[8] = {b0.x, b0.y, b0.z, b0.w, b1.x, b1.y, b1.z, b1.w};
#pragma unroll
      for (int i = 0; i < 8; ++i)
#pragma unroll
        for (int j = 0; j < 8; ++j) acc[i][j] += avv[i] * bvv[j];  // contracts to FMA
    }
  };

  // Prologue: buf0 <- tile 0; regs <- tile 1.
  prefetch(0);
  stage(As0, Bs0);
  prefetch(16);
  __syncthreads();

  // Invariant at loop top: As0/Bs0 hold tile kk; regs hold tile kk+16.
  for (int kk = 0; kk < K_SZ; kk += 32) {
    stage(As1, Bs1);                      // write tile kk+16 (overlaps compute)
    if (kk + 32 < K_SZ) prefetch(kk + 32);
    compute(As0, Bs0);                    // tile kk
    __syncthreads();
    if (kk + 32 < K_SZ) {
      stage(As0, Bs0);                    // write tile kk+32
      if (kk + 48 < K_SZ) prefetch(kk + 48);
    }
    compute(As1, Bs1);                    // tile kk+16
    __syncthreads();
  }

#pragma unroll
  for (int r = 0; r < 8; ++r) {
    const size_t m = M0 + ((r < 4) ? (ty * 4 + r) : (64 + ty * 4 + (r - 4)));
    float* Cp = C + m * H_SZ + N0;
    f32x4 v0 = {acc[r][0], acc[r][1], acc[r][2], acc[r][3]};
    f32x4 v1 = {acc[r][4], acc[r][5], acc[r][6], acc[r][7]};
    // plain (cached) stores: Wx (134 MB) stays resident in 256 MB L3 for the scan
    *reinterpret_cast<f32x4*>(Cp + tx * 4) = v0;
    *reinterpret_cast<f32x4*>(Cp + 64 + tx * 4) = v1;
  }
}

__global__ __launch_bounds__(256) void sgemm_bt(const void* __restrict__ X,
                                                const void* __restrict__ Wm,
                                                float* __restrict__ C) {
  __shared__ float As0[16 * LSTR];  // 8.45 KB each, 33.8 KB total
  __shared__ float Bs0[16 * LSTR];
  __shared__ float As1[16 * LSTR];
  __shared__ float Bs1[16 * LSTR];
  if (detect_bf16(reinterpret_cast<const unsigned int*>(X)))
    gemm_body<true>(X, Wm, C, As0, Bs0, As1, Bs1);
  else
    gemm_body<false>(X, Wm, C, As0, Bs0, As1, Bs1);
}

// ---------------- LIF scan: register-ring loads + rotation-protected stores --
// 1024 blocks x 64 thr; block = (b, 64-h strip), lane = h. Chunk = 8 t; each
// t-row is one coalesced 256 B global load/store (wave-uniform t).
// ring[4][8]: load lookahead 3 chunks (RAW wait distance ~48 vmem ops).
// sdat[2][8]: store payloads, overwritten 2 chunks after their store issues.
// pst[4][8]:  store addresses (full pointers -> the regs ARE the vaddr pair),
//             pst[(c+2)&3] recomputed at end of phase c, i.e. 2 phases after
//             its stores issued -> WAR distance ~48 vmem ops, never vmcnt(0).
#define SCT 8             // timesteps per chunk
#define SNC (T_SZ / SCT)  // 64 chunks

template <bool ISB>
__device__ __forceinline__ void scan_body(
    const float* __restrict__ wx, const void* __restrict__ alpha_p,
    const void* __restrict__ beta_p, const void* __restrict__ a_p,
    const void* __restrict__ b_p, const void* __restrict__ u0p,
    const void* __restrict__ w0p, const void* __restrict__ s0p,
    void* __restrict__ out) {
  const int lane = threadIdx.x;  // 0..63 = h within strip
  const int b = blockIdx.x >> 3;
  const int h = (blockIdx.x & 7) * 64 + lane;

  const float al = fminf(fmaxf(ld1t<ISB>(alpha_p, h), (float)0.8187307530779818),
                         (float)0.9607894391523232);
  const float be = fminf(fmaxf(ld1t<ISB>(beta_p, h), (float)0.9672161004820059),
                         (float)0.9917013044213351);
  const float av = fminf(fmaxf(ld1t<ISB>(a_p, h), -1.0f), 1.0f);
  const float bv = fminf(fmaxf(ld1t<ISB>(b_p, h), 0.0f), 2.0f);
  const float om = __fsub_rn(1.0f, al);

  const int bh = b * H_SZ + h;
  float u = ld1t<ISB>(u0p, bh);
  float w = ld1t<ISB>(w0p, bh);
  float s = ld1t<ISB>(s0p, bh);

  const float* xb = wx + (size_t)b * T_SZ * H_SZ + h;  // + t*H (lane folded in)
  char* ob = reinterpret_cast<char*>(out);
  const size_t ob0 = (size_t)b * T_SZ * H_SZ + h;
  const size_t esz = ISB ? 2u : 4u;

  float ring[4][SCT];
  auto loadc = [&](float* dst, int c) {
#pragma unroll
    for (int j = 0; j < SCT; ++j) {
      int t = c * SCT + j;
      t = (t < T_SZ) ? t : (T_SZ - 1);  // wave-uniform clamp, branchless
      dst[j] = xb[(size_t)t * H_SZ];
    }
  };

  float sdat[2][SCT];  // store payload rotation (2 chunks deep)
  char* pst[4][SCT];   // store address rotation (4 chunks deep)
  auto calca = [&](char** dst, int c) {
#pragma unroll
    for (int j = 0; j < SCT; ++j)
      dst[j] = ob + (ob0 + (size_t)(c * SCT + j) * H_SZ) * esz;  // OOB ptrs never deref'd
  };

  loadc(ring[0], 0); loadc(ring[1], 1); loadc(ring[2], 2); loadc(ring[3], 3);
  calca(pst[0], 0); calca(pst[1], 1); calca(pst[2], 2); calca(pst[3], 3);

  for (int c0 = 0; c0 < SNC; c0 += 4) {
#pragma unroll
    for (int p = 0; p < 4; ++p) {  // static phase index -> static registers
      const int c = c0 + p;        // chunk; c & 3 == p
      const int q = p & 1;
#pragma unroll
      for (int j = 0; j < SCT; ++j) {
        const float cur = ring[p][j];
        // numpy left-to-right, each op individually rounded (no FMA contraction)
        w = __fadd_rn(__fadd_rn(__fmul_rn(be, w), __fmul_rn(av, u)), __fmul_rn(bv, s));
        u = __fadd_rn(__fmul_rn(al, __fsub_rn(u, s)), __fmul_rn(om, __fsub_rn(cur, w)));
        const bool sp = (u > 1.0f);
        s = sp ? 1.0f : 0.0f;
        // payload: fp32 spike value, or bf16 bit pattern (0x3F80/0) by select — no cvt temp
        sdat[q][j] = ISB ? __uint_as_float(sp ? 0x3F80u : 0u) : s;
      }
      // grouped stores; data regs rotate 2 chunks, addr regs rotate 4 chunks
#pragma unroll
      for (int j = 0; j < SCT; ++j) {
        if constexpr (ISB)
          *reinterpret_cast<unsigned short*>(pst[p][j]) =
              (unsigned short)__float_as_uint(sdat[q][j]);
        else
          *reinterpret_cast<float*>(pst[p][j]) = sdat[q][j];
      }
      loadc(ring[p], c + 4);           // refill just-consumed phase (clamped past T)
      calca(pst[(p + 2) & 3], c + 2);  // rewrite addrs used 2 phases ago, for chunk c+2
    }
  }
}

__global__ __launch_bounds__(64) void lif_scan(
    const float* __restrict__ wx, const void* __restrict__ X,
    const void* __restrict__ alpha_p, const void* __restrict__ beta_p,
    const void* __restrict__ a_p, const void* __restrict__ b_p,
    const void* __restrict__ u0p, const void* __restrict__ w0p,
    const void* __restrict__ s0p, void* __restrict__ out) {
  if (detect_bf16(reinterpret_cast<const unsigned int*>(X)))
    scan_body<true>(wx, alpha_p, beta_p, a_p, b_p, u0p, w0p, s0p, out);
  else
    scan_body<false>(wx, alpha_p, beta_p, a_p, b_p, u0p, w0p, s0p, out);
}

extern "C" void kernel_launch(void* const* d_in, const int* in_sizes, int n_in,
                              void* d_out, int out_size, void* d_ws, size_t ws_size,
                              hipStream_t stream) {
  const void* X = d_in[0];   // x [B,T,I]
  const void* Wm = d_in[1];  // W [H,I]
  float* ws = reinterpret_cast<float*>(d_ws);  // Wx fp32 [B,T,H]

  sgemm_bt<<<dim3((M_SZ / 128) * (H_SZ / 128)), dim3(256), 0, stream>>>(X, Wm, ws);

  lif_scan<<<dim3(B_SZ * 8), dim3(64), 0, stream>>>(
      ws, X, d_in[2], d_in[3], d_in[4], d_in[5], d_in[6], d_in[7], d_in[8], d_out);
}

// Round 2
// 642.871 us; speedup vs baseline: 1.1786x; 1.1786x over previous
//
#include <hip/hip_runtime.h>
#include <hip/hip_bf16.h>

// adLIF: Wx = x @ W^T (fp32 FMA GEMM, strictly sequential-K accumulation to
// mirror BLAS bit-for-bit), then sequential LIF scan over T with rounding-exact
// fp32 ops. Input dtype (fp32 vs bf16) detected ON DEVICE from x's bit pattern.
// r12 GEMM: r6 structure VERBATIM (single-buffer LDS, VGPR 116, 409 us measured).
//   r11's double-buffer hit the 128-VGPR occupancy cliff (200 VGPR, 2 waves/SIMD,
//   620 us) -> reverted. Only deviation from r6: plain cached C stores (not
//   nontemporal) so Wx stays L3-resident for the scan. RULE: keep VGPR <= 128.
// r12 scan: r11's rotation-protected stores helped (213 -> ~138 us). Deepen:
//   ring 4 -> 8 chunks (lookahead 7 chunks ~ 56 loads in flight), store payload
//   rotation 2 -> 4 chunks (WAR distance ~64 vmem ops), store addresses as
//   32-bit offsets from uniform base (saddr form, halves addr VGPRs).

#define M_SZ 65536  // B*T
#define H_SZ 512
#define K_SZ 512
#define B_SZ 128
#define T_SZ 512
#define LSTR 132  // LDS row stride (dwords), %32==4: staging writes conflict-free

typedef __attribute__((ext_vector_type(4))) float f32x4;

__device__ __forceinline__ bool detect_bf16(const unsigned int* __restrict__ w) {
  int c = 0;
#pragma unroll
  for (int i = 0; i < 64; ++i) {
    unsigned int e = (w[i] >> 7) & 0xffu;
    c += (e >= 115u && e <= 131u) ? 1 : 0;
  }
  return c > 32;  // bf16 exponents cluster in [115,131]; fp32 mantissa bits don't
}

template <bool ISB>
__device__ __forceinline__ f32x4 ld4t(const void* __restrict__ p, size_t off) {
  if constexpr (!ISB) {
    return *reinterpret_cast<const f32x4*>(reinterpret_cast<const float*>(p) + off);
  } else {
    uint2 v = *reinterpret_cast<const uint2*>(reinterpret_cast<const unsigned short*>(p) + off);
    f32x4 r;
    r.x = __uint_as_float((v.x & 0xffffu) << 16);
    r.y = __uint_as_float(v.x & 0xffff0000u);
    r.z = __uint_as_float((v.y & 0xffffu) << 16);
    r.w = __uint_as_float(v.y & 0xffff0000u);
    return r;
  }
}

template <bool ISB>
__device__ __forceinline__ float ld1t(const void* __restrict__ p, int i) {
  if constexpr (!ISB) return reinterpret_cast<const float*>(p)[i];
  return __uint_as_float((unsigned int)(reinterpret_cast<const unsigned short*>(p)[i]) << 16);
}

// ---------------- GEMM: C[m][n] = sum_k X[m][k]*W[n][k], fp32, k ascending ----
template <bool ISB>
__device__ __forceinline__ void gemm_body(const void* __restrict__ X,
                                          const void* __restrict__ Wm,
                                          float* __restrict__ C,
                                          float* __restrict__ As,
                                          float* __restrict__ Bs) {
  const int tid = threadIdx.x;
  const int r0 = tid >> 2;       // 0..63: staged row
  const int q0 = (tid & 3) * 4;  // 0,4,8,12: k-group
  const int tx = tid & 15;       // n-group
  const int ty = tid >> 4;       // m-group
  const size_t M0 = (size_t)(blockIdx.x >> 2) * 128;
  const int N0 = (blockIdx.x & 3) * 128;

  float acc[8][8];
#pragma unroll
  for (int i = 0; i < 8; ++i)
#pragma unroll
    for (int j = 0; j < 8; ++j) acc[i][j] = 0.0f;

  const size_t aoff0 = (M0 + r0) * K_SZ + q0;
  const size_t aoff1 = (M0 + r0 + 64) * K_SZ + q0;
  const size_t boff0 = (size_t)(N0 + r0) * K_SZ + q0;
  const size_t boff1 = (size_t)(N0 + r0 + 64) * K_SZ + q0;

  f32x4 pa0 = ld4t<ISB>(X, aoff0), pa1 = ld4t<ISB>(X, aoff1);
  f32x4 pb0 = ld4t<ISB>(Wm, boff0), pb1 = ld4t<ISB>(Wm, boff1);

  for (int kk = 0; kk < K_SZ; kk += 16) {
    __syncthreads();  // prior compute done -> LDS free
    As[(q0 + 0) * LSTR + r0] = pa0.x; As[(q0 + 1) * LSTR + r0] = pa0.y;
    As[(q0 + 2) * LSTR + r0] = pa0.z; As[(q0 + 3) * LSTR + r0] = pa0.w;
    As[(q0 + 0) * LSTR + r0 + 64] = pa1.x; As[(q0 + 1) * LSTR + r0 + 64] = pa1.y;
    As[(q0 + 2) * LSTR + r0 + 64] = pa1.z; As[(q0 + 3) * LSTR + r0 + 64] = pa1.w;
    Bs[(q0 + 0) * LSTR + r0] = pb0.x; Bs[(q0 + 1) * LSTR + r0] = pb0.y;
    Bs[(q0 + 2) * LSTR + r0] = pb0.z; Bs[(q0 + 3) * LSTR + r0] = pb0.w;
    Bs[(q0 + 0) * LSTR + r0 + 64] = pb1.x; Bs[(q0 + 1) * LSTR + r0 + 64] = pb1.y;
    Bs[(q0 + 2) * LSTR + r0 + 64] = pb1.z; Bs[(q0 + 3) * LSTR + r0 + 64] = pb1.w;
    __syncthreads();  // tile ready
    if (kk + 16 < K_SZ) {  // prefetch next chunk; in flight across compute
      pa0 = ld4t<ISB>(X, aoff0 + kk + 16); pa1 = ld4t<ISB>(X, aoff1 + kk + 16);
      pb0 = ld4t<ISB>(Wm, boff0 + kk + 16); pb1 = ld4t<ISB>(Wm, boff1 + kk + 16);
    }
#pragma unroll
    for (int k = 0; k < 16; ++k) {
      const f32x4 a0 = *reinterpret_cast<const f32x4*>(As + k * LSTR + ty * 4);
      const f32x4 a1 = *reinterpret_cast<const f32x4*>(As + k * LSTR + 64 + ty * 4);
      const f32x4 b0 = *reinterpret_cast<const f32x4*>(Bs + k * LSTR + tx * 4);
      const f32x4 b1 = *reinterpret_cast<const f32x4*>(Bs + k * LSTR + 64 + tx * 4);
      const float av[8] = {a0.x, a0.y, a0.z, a0.w, a1.x, a1.y, a1.z, a1.w};
      const float bv[8] = {b0.x, b0.y, b0.z, b0.w, b1.x, b1.y, b1.z, b1.w};
#pragma unroll
      for (int i = 0; i < 8; ++i)
#pragma unroll
        for (int j = 0; j < 8; ++j) acc[i][j] += av[i] * bv[j];  // contracts to FMA
    }
  }

#pragma unroll
  for (int r = 0; r < 8; ++r) {
    const size_t m = M0 + ((r < 4) ? (ty * 4 + r) : (64 + ty * 4 + (r - 4)));
    float* Cp = C + m * H_SZ + N0;
    f32x4 v0 = {acc[r][0], acc[r][1], acc[r][2], acc[r][3]};
    f32x4 v1 = {acc[r][4], acc[r][5], acc[r][6], acc[r][7]};
    // plain (cached) stores: Wx (134 MB) stays resident in 256 MB L3 for the scan
    *reinterpret_cast<f32x4*>(Cp + tx * 4) = v0;
    *reinterpret_cast<f32x4*>(Cp + 64 + tx * 4) = v1;
  }
}

__global__ __launch_bounds__(256) void sgemm_bt(const void* __restrict__ X,
                                                const void* __restrict__ Wm,
                                                float* __restrict__ C) {
  __shared__ float As[16 * LSTR];  // 8.45 KB
  __shared__ float Bs[16 * LSTR];  // 8.45 KB
  if (detect_bf16(reinterpret_cast<const unsigned int*>(X)))
    gemm_body<true>(X, Wm, C, As, Bs);
  else
    gemm_body<false>(X, Wm, C, As, Bs);
}

// ---------------- LIF scan: deep register-ring loads + rotated stores --------
// 1024 blocks x 64 thr; block = (b, 64-h strip), lane = h. Chunk = 8 t; each
// t-row is one coalesced 256 B global load/store (wave-uniform t).
// ring[8][8]: load lookahead 7 chunks (~56 loads in flight -> vmem queue full).
// sdat[4][8]: store payloads, overwritten 4 chunks after their store issues
//             (WAR distance ~64 vmem ops -> never forces a near drain).
// pst[4][8]:  store addresses as u32 byte offsets from uniform out base
//             (saddr store form, 1 VGPR/addr); bank (c&3) recomputed 2 chunks
//             after last use.
#define SCT 8             // timesteps per chunk
#define SNC (T_SZ / SCT)  // 64 chunks
#define RD 8              // ring depth in chunks

template <bool ISB>
__device__ __forceinline__ void scan_body(
    const float* __restrict__ wx, const void* __restrict__ alpha_p,
    const void* __restrict__ beta_p, const void* __restrict__ a_p,
    const void* __restrict__ b_p, const void* __restrict__ u0p,
    const void* __restrict__ w0p, const void* __restrict__ s0p,
    void* __restrict__ out) {
  const int lane = threadIdx.x;  // 0..63 = h within strip
  const int b = blockIdx.x >> 3;
  const int h = (blockIdx.x & 7) * 64 + lane;

  const float al = fminf(fmaxf(ld1t<ISB>(alpha_p, h), (float)0.8187307530779818),
                         (float)0.9607894391523232);
  const float be = fminf(fmaxf(ld1t<ISB>(beta_p, h), (float)0.9672161004820059),
                         (float)0.9917013044213351);
  const float av = fminf(fmaxf(ld1t<ISB>(a_p, h), -1.0f), 1.0f);
  const float bv = fminf(fmaxf(ld1t<ISB>(b_p, h), 0.0f), 2.0f);
  const float om = __fsub_rn(1.0f, al);

  const int bh = b * H_SZ + h;
  float u = ld1t<ISB>(u0p, bh);
  float w = ld1t<ISB>(w0p, bh);
  float s = ld1t<ISB>(s0p, bh);

  const float* xb = wx + (size_t)b * T_SZ * H_SZ + h;  // + t*H (lane folded in)
  char* ob = reinterpret_cast<char*>(out);
  // u32 byte offset of (b, t=0, h); whole out buffer < 4 GB so offsets fit u32
  const unsigned int esz = ISB ? 2u : 4u;
  const unsigned int ob0b = (unsigned int)(((size_t)b * T_SZ * H_SZ + h) * esz);

  float ring[RD][SCT];
  auto loadc = [&](float* dst, int c) {
#pragma unroll
    for (int j = 0; j < SCT; ++j) {
      int t = c * SCT + j;
      t = (t < T_SZ) ? t : (T_SZ - 1);  // wave-uniform clamp, branchless
      dst[j] = xb[(size_t)t * H_SZ];
    }
  };

  float sdat[4][SCT];        // store payload rotation (4 chunks deep)
  unsigned int pst[4][SCT];  // store byte-offset rotation (4 chunks deep)
  auto calca = [&](unsigned int* dst, int c) {
#pragma unroll
    for (int j = 0; j < SCT; ++j)
      dst[j] = ob0b + (unsigned int)((c * SCT + j) * H_SZ) * esz;  // OOB offs never deref'd
  };

#pragma unroll
  for (int i = 0; i < RD; ++i) loadc(ring[i], i);
#pragma unroll
  for (int i = 0; i < 4; ++i) calca(pst[i], i);

  for (int c0 = 0; c0 < SNC; c0 += RD) {
#pragma unroll
    for (int p = 0; p < RD; ++p) {  // static phase index -> static registers
      const int c = c0 + p;         // chunk; c & 7 == p, c & 3 == p & 3
      const int q = p & 3;
#pragma unroll
      for (int j = 0; j < SCT; ++j) {
        const float cur = ring[p][j];
        // numpy left-to-right, each op individually rounded (no FMA contraction)
        w = __fadd_rn(__fadd_rn(__fmul_rn(be, w), __fmul_rn(av, u)), __fmul_rn(bv, s));
        u = __fadd_rn(__fmul_rn(al, __fsub_rn(u, s)), __fmul_rn(om, __fsub_rn(cur, w)));
        const bool sp = (u > 1.0f);
        s = sp ? 1.0f : 0.0f;
        // payload: fp32 spike value, or bf16 bit pattern (0x3F80/0) by select
        sdat[q][j] = ISB ? __uint_as_float(sp ? 0x3F80u : 0u) : s;
      }
      // grouped stores; payload regs rotate 4 chunks, addr regs rotate 4 chunks
#pragma unroll
      for (int j = 0; j < SCT; ++j) {
        if constexpr (ISB)
          *reinterpret_cast<unsigned short*>(ob + pst[q][j]) =
              (unsigned short)__float_as_uint(sdat[q][j]);
        else
          *reinterpret_cast<float*>(ob + pst[q][j]) = sdat[q][j];
      }
      loadc(ring[p], c + RD);          // refill just-consumed phase (clamped past T)
      calca(pst[(q + 2) & 3], c + 2);  // rewrite offs used 2 chunks ago, for chunk c+2
    }
  }
}

__global__ __launch_bounds__(64) void lif_scan(
    const float* __restrict__ wx, const void* __restrict__ X,
    const void* __restrict__ alpha_p, const void* __restrict__ beta_p,
    const void* __restrict__ a_p, const void* __restrict__ b_p,
    const void* __restrict__ u0p, const void* __restrict__ w0p,
    const void* __restrict__ s0p, void* __restrict__ out) {
  if (detect_bf16(reinterpret_cast<const unsigned int*>(X)))
    scan_body<true>(wx, alpha_p, beta_p, a_p, b_p, u0p, w0p, s0p, out);
  else
    scan_body<false>(wx, alpha_p, beta_p, a_p, b_p, u0p, w0p, s0p, out);
}

extern "C" void kernel_launch(void* const* d_in, const int* in_sizes, int n_in,
                              void* d_out, int out_size, void* d_ws, size_t ws_size,
                              hipStream_t stream) {
  const void* X = d_in[0];   // x [B,T,I]
  const void* Wm = d_in[1];  // W [H,I]
  float* ws = reinterpret_cast<float*>(d_ws);  // Wx fp32 [B,T,H]

  sgemm_bt<<<dim3((M_SZ / 128) * (H_SZ / 128)), dim3(256), 0, stream>>>(X, Wm, ws);

  lif_scan<<<dim3(B_SZ * 8), dim3(64), 0, stream>>>(
      ws, X, d_in[2], d_in[3], d_in[4], d_in[5], d_in[6], d_in[7], d_in[8], d_out);
}

// Round 3
// 621.895 us; speedup vs baseline: 1.2183x; 1.0337x over previous
//
#include <hip/hip_runtime.h>
#include <hip/hip_bf16.h>

// adLIF: Wx = x @ W^T (fp32 FMA GEMM, strictly sequential-K accumulation to
// mirror BLAS bit-for-bit), then sequential LIF scan over T with rounding-exact
// fp32 ops. Input dtype (fp32 vs bf16) detected ON DEVICE from x's bit pattern.
// r13 GEMM: UNCHANGED from r12 (r6 structure, VGPR 116, 432 us with cached
//   C-stores; nontemporal saves 23 us here -> candidate next round once the
//   scan's L3-residency question is settled). RULE: keep VGPR <= 128.
// r13 scan: load-address WAR fix. r12 evidence: 650 cyc/timestep == ~1 load in
//   flight; the ring DATA regs rotated but load ADDRESSES were compiler temps
//   (VMEM addr regs can't be overwritten until the op completes -> each load
//   serialized on the previous one's completion). Now: persistent u32 byte
//   offsets loff[4][8] off a wave-uniform SGPR base (saddr form); refill does
//   loff += const (clamped) AFTER its old load's data was consumed -> WAR-free,
//   ~32 loads genuinely in flight. Ring back to 4 (RD=8 regressed: reg pressure).

#define M_SZ 65536  // B*T
#define H_SZ 512
#define K_SZ 512
#define B_SZ 128
#define T_SZ 512
#define LSTR 132  // LDS row stride (dwords), %32==4: staging writes conflict-free

typedef __attribute__((ext_vector_type(4))) float f32x4;

__device__ __forceinline__ bool detect_bf16(const unsigned int* __restrict__ w) {
  int c = 0;
#pragma unroll
  for (int i = 0; i < 64; ++i) {
    unsigned int e = (w[i] >> 7) & 0xffu;
    c += (e >= 115u && e <= 131u) ? 1 : 0;
  }
  return c > 32;  // bf16 exponents cluster in [115,131]; fp32 mantissa bits don't
}

template <bool ISB>
__device__ __forceinline__ f32x4 ld4t(const void* __restrict__ p, size_t off) {
  if constexpr (!ISB) {
    return *reinterpret_cast<const f32x4*>(reinterpret_cast<const float*>(p) + off);
  } else {
    uint2 v = *reinterpret_cast<const uint2*>(reinterpret_cast<const unsigned short*>(p) + off);
    f32x4 r;
    r.x = __uint_as_float((v.x & 0xffffu) << 16);
    r.y = __uint_as_float(v.x & 0xffff0000u);
    r.z = __uint_as_float((v.y & 0xffffu) << 16);
    r.w = __uint_as_float(v.y & 0xffff0000u);
    return r;
  }
}

template <bool ISB>
__device__ __forceinline__ float ld1t(const void* __restrict__ p, int i) {
  if constexpr (!ISB) return reinterpret_cast<const float*>(p)[i];
  return __uint_as_float((unsigned int)(reinterpret_cast<const unsigned short*>(p)[i]) << 16);
}

// ---------------- GEMM: C[m][n] = sum_k X[m][k]*W[n][k], fp32, k ascending ----
template <bool ISB>
__device__ __forceinline__ void gemm_body(const void* __restrict__ X,
                                          const void* __restrict__ Wm,
                                          float* __restrict__ C,
                                          float* __restrict__ As,
                                          float* __restrict__ Bs) {
  const int tid = threadIdx.x;
  const int r0 = tid >> 2;       // 0..63: staged row
  const int q0 = (tid & 3) * 4;  // 0,4,8,12: k-group
  const int tx = tid & 15;       // n-group
  const int ty = tid >> 4;       // m-group
  const size_t M0 = (size_t)(blockIdx.x >> 2) * 128;
  const int N0 = (blockIdx.x & 3) * 128;

  float acc[8][8];
#pragma unroll
  for (int i = 0; i < 8; ++i)
#pragma unroll
    for (int j = 0; j < 8; ++j) acc[i][j] = 0.0f;

  const size_t aoff0 = (M0 + r0) * K_SZ + q0;
  const size_t aoff1 = (M0 + r0 + 64) * K_SZ + q0;
  const size_t boff0 = (size_t)(N0 + r0) * K_SZ + q0;
  const size_t boff1 = (size_t)(N0 + r0 + 64) * K_SZ + q0;

  f32x4 pa0 = ld4t<ISB>(X, aoff0), pa1 = ld4t<ISB>(X, aoff1);
  f32x4 pb0 = ld4t<ISB>(Wm, boff0), pb1 = ld4t<ISB>(Wm, boff1);

  for (int kk = 0; kk < K_SZ; kk += 16) {
    __syncthreads();  // prior compute done -> LDS free
    As[(q0 + 0) * LSTR + r0] = pa0.x; As[(q0 + 1) * LSTR + r0] = pa0.y;
    As[(q0 + 2) * LSTR + r0] = pa0.z; As[(q0 + 3) * LSTR + r0] = pa0.w;
    As[(q0 + 0) * LSTR + r0 + 64] = pa1.x; As[(q0 + 1) * LSTR + r0 + 64] = pa1.y;
    As[(q0 + 2) * LSTR + r0 + 64] = pa1.z; As[(q0 + 3) * LSTR + r0 + 64] = pa1.w;
    Bs[(q0 + 0) * LSTR + r0] = pb0.x; Bs[(q0 + 1) * LSTR + r0] = pb0.y;
    Bs[(q0 + 2) * LSTR + r0] = pb0.z; Bs[(q0 + 3) * LSTR + r0] = pb0.w;
    Bs[(q0 + 0) * LSTR + r0 + 64] = pb1.x; Bs[(q0 + 1) * LSTR + r0 + 64] = pb1.y;
    Bs[(q0 + 2) * LSTR + r0 + 64] = pb1.z; Bs[(q0 + 3) * LSTR + r0 + 64] = pb1.w;
    __syncthreads();  // tile ready
    if (kk + 16 < K_SZ) {  // prefetch next chunk; in flight across compute
      pa0 = ld4t<ISB>(X, aoff0 + kk + 16); pa1 = ld4t<ISB>(X, aoff1 + kk + 16);
      pb0 = ld4t<ISB>(Wm, boff0 + kk + 16); pb1 = ld4t<ISB>(Wm, boff1 + kk + 16);
    }
#pragma unroll
    for (int k = 0; k < 16; ++k) {
      const f32x4 a0 = *reinterpret_cast<const f32x4*>(As + k * LSTR + ty * 4);
      const f32x4 a1 = *reinterpret_cast<const f32x4*>(As + k * LSTR + 64 + ty * 4);
      const f32x4 b0 = *reinterpret_cast<const f32x4*>(Bs + k * LSTR + tx * 4);
      const f32x4 b1 = *reinterpret_cast<const f32x4*>(Bs + k * LSTR + 64 + tx * 4);
      const float av[8] = {a0.x, a0.y, a0.z, a0.w, a1.x, a1.y, a1.z, a1.w};
      const float bv[8] = {b0.x, b0.y, b0.z, b0.w, b1.x, b1.y, b1.z, b1.w};
#pragma unroll
      for (int i = 0; i < 8; ++i)
#pragma unroll
        for (int j = 0; j < 8; ++j) acc[i][j] += av[i] * bv[j];  // contracts to FMA
    }
  }

#pragma unroll
  for (int r = 0; r < 8; ++r) {
    const size_t m = M0 + ((r < 4) ? (ty * 4 + r) : (64 + ty * 4 + (r - 4)));
    float* Cp = C + m * H_SZ + N0;
    f32x4 v0 = {acc[r][0], acc[r][1], acc[r][2], acc[r][3]};
    f32x4 v1 = {acc[r][4], acc[r][5], acc[r][6], acc[r][7]};
    // plain (cached) stores: Wx (134 MB) stays resident in 256 MB L3 for the scan
    *reinterpret_cast<f32x4*>(Cp + tx * 4) = v0;
    *reinterpret_cast<f32x4*>(Cp + 64 + tx * 4) = v1;
  }
}

__global__ __launch_bounds__(256) void sgemm_bt(const void* __restrict__ X,
                                                const void* __restrict__ Wm,
                                                float* __restrict__ C) {
  __shared__ float As[16 * LSTR];  // 8.45 KB
  __shared__ float Bs[16 * LSTR];  // 8.45 KB
  if (detect_bf16(reinterpret_cast<const unsigned int*>(X)))
    gemm_body<true>(X, Wm, C, As, Bs);
  else
    gemm_body<false>(X, Wm, C, As, Bs);
}

// ---------------- LIF scan: WAR-free rotating loads AND stores ---------------
// 1024 blocks x 64 thr; block = (b, 64-h strip), lane = h. Chunk = 8 t; each
// t-row is one coalesced 256 B global load/store (wave-uniform t step).
// loff[4][8]: PERSISTENT u32 load byte-offsets off wave-uniform base (saddr
//             form). Refill: loff += 64 KB (v_min_u32 clamp) — overwrite only
//             after that slot's previous load was consumed -> zero WAR waits,
//             ~24-32 loads genuinely in flight.
// ring[4][8]: load data, overwritten by the refill right after consumption.
// sdat[2][8]: store payloads, overwritten 2 chunks (~32 vmem ops) later.
// pst[4][8]:  store u32 byte-offsets, bank (c&3) recomputed 2 chunks after use.
#define SCT 8             // timesteps per chunk
#define SNC (T_SZ / SCT)  // 64 chunks
#define RD 4              // ring depth in chunks
#define LDELTA ((unsigned int)(RD * SCT * H_SZ * 4))  // 65536 B: slot offset step

template <bool ISB>
__device__ __forceinline__ void scan_body(
    const float* __restrict__ wx, const void* __restrict__ alpha_p,
    const void* __restrict__ beta_p, const void* __restrict__ a_p,
    const void* __restrict__ b_p, const void* __restrict__ u0p,
    const void* __restrict__ w0p, const void* __restrict__ s0p,
    void* __restrict__ out) {
  const int lane = threadIdx.x;  // 0..63 = h within strip
  const int b = blockIdx.x >> 3;
  const int h = (blockIdx.x & 7) * 64 + lane;

  const float al = fminf(fmaxf(ld1t<ISB>(alpha_p, h), (float)0.8187307530779818),
                         (float)0.9607894391523232);
  const float be = fminf(fmaxf(ld1t<ISB>(beta_p, h), (float)0.9672161004820059),
                         (float)0.9917013044213351);
  const float av = fminf(fmaxf(ld1t<ISB>(a_p, h), -1.0f), 1.0f);
  const float bv = fminf(fmaxf(ld1t<ISB>(b_p, h), 0.0f), 2.0f);
  const float om = __fsub_rn(1.0f, al);

  const int bh = b * H_SZ + h;
  float u = ld1t<ISB>(u0p, bh);
  float w = ld1t<ISB>(w0p, bh);
  float s = ld1t<ISB>(s0p, bh);

  // wave-uniform bases (b is uniform per block) -> saddr-form vmem, u32 voffsets
  const char* xbase = reinterpret_cast<const char*>(wx + (size_t)b * T_SZ * H_SZ);
  char* ob = reinterpret_cast<char*>(out);
  const unsigned int esz = ISB ? 2u : 4u;
  const unsigned int h4 = (unsigned int)h * 4u;
  const unsigned int ob0b = (unsigned int)(((size_t)b * T_SZ * H_SZ + h) * esz);
  const unsigned int lmax = h4 + (unsigned int)((T_SZ - 1) * H_SZ) * 4u;  // clamp target

  float ring[RD][SCT];        // load data rotation
  unsigned int loff[RD][SCT];  // PERSISTENT load offsets (the addr regs themselves)
  float sdat[2][SCT];          // store payload rotation (2 chunks deep)
  unsigned int pst[4][SCT];    // store offset rotation (4 chunks deep)

  auto calca = [&](unsigned int* dst, int c) {
#pragma unroll
    for (int j = 0; j < SCT; ++j)
      dst[j] = ob0b + (unsigned int)((c * SCT + j) * H_SZ) * esz;  // OOB offs never deref'd
  };

#pragma unroll
  for (int i = 0; i < RD; ++i)
#pragma unroll
    for (int j = 0; j < SCT; ++j) {  // init offsets + issue first RD chunks
      loff[i][j] = h4 + (unsigned int)((i * SCT + j) * H_SZ) * 4u;
      ring[i][j] = *reinterpret_cast<const float*>(xbase + loff[i][j]);
    }
#pragma unroll
  for (int i = 0; i < 4; ++i) calca(pst[i], i);

  for (int c0 = 0; c0 < SNC; c0 += RD) {
#pragma unroll
    for (int p = 0; p < RD; ++p) {  // static phase index -> static registers
      const int c = c0 + p;         // chunk; c & 3 == p
      const int q = p & 1;
#pragma unroll
      for (int j = 0; j < SCT; ++j) {
        const float cur = ring[p][j];
        // numpy left-to-right, each op individually rounded (no FMA contraction)
        w = __fadd_rn(__fadd_rn(__fmul_rn(be, w), __fmul_rn(av, u)), __fmul_rn(bv, s));
        u = __fadd_rn(__fmul_rn(al, __fsub_rn(u, s)), __fmul_rn(om, __fsub_rn(cur, w)));
        const bool sp = (u > 1.0f);
        s = sp ? 1.0f : 0.0f;
        // payload: fp32 spike value, or bf16 bit pattern (0x3F80/0) by select
        sdat[q][j] = ISB ? __uint_as_float(sp ? 0x3F80u : 0u) : s;
      }
      // grouped stores for chunk c (addresses prepared >=2 chunks ago)
#pragma unroll
      for (int j = 0; j < SCT; ++j) {
        if constexpr (ISB)
          *reinterpret_cast<unsigned short*>(ob + pst[p][j]) =
              (unsigned short)__float_as_uint(sdat[q][j]);
        else
          *reinterpret_cast<float*>(ob + pst[p][j]) = sdat[q][j];
      }
      // refill slot p with chunk c+RD: advance persistent offsets (WAR-free:
      // the load that used loff[p][j] was consumed above), clamp to last row
#pragma unroll
      for (int j = 0; j < SCT; ++j) {
        unsigned int o = loff[p][j] + LDELTA;
        o = (o > lmax) ? lmax : o;  // v_min_u32: branchless, keeps in-bounds
        loff[p][j] = o;
        ring[p][j] = *reinterpret_cast<const float*>(xbase + o);
      }
      calca(pst[(p + 2) & 3], c + 2);  // rewrite offs used 2 chunks ago, for chunk c+2
    }
  }
}

__global__ __launch_bounds__(64) void lif_scan(
    const float* __restrict__ wx, const void* __restrict__ X,
    const void* __restrict__ alpha_p, const void* __restrict__ beta_p,
    const void* __restrict__ a_p, const void* __restrict__ b_p,
    const void* __restrict__ u0p, const void* __restrict__ w0p,
    const void* __restrict__ s0p, void* __restrict__ out) {
  if (detect_bf16(reinterpret_cast<const unsigned int*>(X)))
    scan_body<true>(wx, alpha_p, beta_p, a_p, b_p, u0p, w0p, s0p, out);
  else
    scan_body<false>(wx, alpha_p, beta_p, a_p, b_p, u0p, w0p, s0p, out);
}

extern "C" void kernel_launch(void* const* d_in, const int* in_sizes, int n_in,
                              void* d_out, int out_size, void* d_ws, size_t ws_size,
                              hipStream_t stream) {
  const void* X = d_in[0];   // x [B,T,I]
  const void* Wm = d_in[1];  // W [H,I]
  float* ws = reinterpret_cast<float*>(d_ws);  // Wx fp32 [B,T,H]

  sgemm_bt<<<dim3((M_SZ / 128) * (H_SZ / 128)), dim3(256), 0, stream>>>(X, Wm, ws);

  lif_scan<<<dim3(B_SZ * 8), dim3(64), 0, stream>>>(
      ws, X, d_in[2], d_in[3], d_in[4], d_in[5], d_in[6], d_in[7], d_in[8], d_out);
}

// Round 4
// 618.092 us; speedup vs baseline: 1.2258x; 1.0062x over previous
//
#include <hip/hip_runtime.h>
#include <hip/hip_bf16.h>

// adLIF: Wx = x @ W^T (fp32 FMA GEMM, strictly sequential-K accumulation to
// mirror BLAS bit-for-bit), then sequential LIF scan over T with rounding-exact
// fp32 ops. Input dtype (fp32 vs bf16) detected ON DEVICE from x's bit pattern.
// r14 GEMM: UNCHANGED from r13 (r6 structure, VGPR 116, ~418-432 us, cached
//   C-stores). RULE: keep VGPR <= 128.
// r14 scan: PRODUCER-CONSUMER. Evidence r11-r13: every register-ring variant
//   runs at ~1 load-latency per timestep (138 us = 512x650cy, 204 us =
//   512x950cy) -> single-wave load pipelining never materializes regardless of
//   register rotation. Structural fix: 8 waves/block. Wave 0 (consumer) runs
//   the recurrence touching ONLY LDS (~30 cyc/step); waves 1-7 (producers)
//   stage Wx rows into a double-buffered LDS in-ring and drain spike rows from
//   an LDS out-ring to global. Superchunk = 32 t-rows; one __syncthreads per
//   superchunk; A/B parity: consumer(sc) || producers fill(sc+1) + drain(sc-1).
//   7-way cross-wave memory parallelism even if per-wave loads serialize.

#define M_SZ 65536  // B*T
#define H_SZ 512
#define K_SZ 512
#define B_SZ 128
#define T_SZ 512
#define LSTR 132  // LDS row stride (dwords), %32==4: staging writes conflict-free

typedef __attribute__((ext_vector_type(4))) float f32x4;

__device__ __forceinline__ bool detect_bf16(const unsigned int* __restrict__ w) {
  int c = 0;
#pragma unroll
  for (int i = 0; i < 64; ++i) {
    unsigned int e = (w[i] >> 7) & 0xffu;
    c += (e >= 115u && e <= 131u) ? 1 : 0;
  }
  return c > 32;  // bf16 exponents cluster in [115,131]; fp32 mantissa bits don't
}

template <bool ISB>
__device__ __forceinline__ f32x4 ld4t(const void* __restrict__ p, size_t off) {
  if constexpr (!ISB) {
    return *reinterpret_cast<const f32x4*>(reinterpret_cast<const float*>(p) + off);
  } else {
    uint2 v = *reinterpret_cast<const uint2*>(reinterpret_cast<const unsigned short*>(p) + off);
    f32x4 r;
    r.x = __uint_as_float((v.x & 0xffffu) << 16);
    r.y = __uint_as_float(v.x & 0xffff0000u);
    r.z = __uint_as_float((v.y & 0xffffu) << 16);
    r.w = __uint_as_float(v.y & 0xffff0000u);
    return r;
  }
}

template <bool ISB>
__device__ __forceinline__ float ld1t(const void* __restrict__ p, int i) {
  if constexpr (!ISB) return reinterpret_cast<const float*>(p)[i];
  return __uint_as_float((unsigned int)(reinterpret_cast<const unsigned short*>(p)[i]) << 16);
}

// ---------------- GEMM: C[m][n] = sum_k X[m][k]*W[n][k], fp32, k ascending ----
template <bool ISB>
__device__ __forceinline__ void gemm_body(const void* __restrict__ X,
                                          const void* __restrict__ Wm,
                                          float* __restrict__ C,
                                          float* __restrict__ As,
                                          float* __restrict__ Bs) {
  const int tid = threadIdx.x;
  const int r0 = tid >> 2;       // 0..63: staged row
  const int q0 = (tid & 3) * 4;  // 0,4,8,12: k-group
  const int tx = tid & 15;       // n-group
  const int ty = tid >> 4;       // m-group
  const size_t M0 = (size_t)(blockIdx.x >> 2) * 128;
  const int N0 = (blockIdx.x & 3) * 128;

  float acc[8][8];
#pragma unroll
  for (int i = 0; i < 8; ++i)
#pragma unroll
    for (int j = 0; j < 8; ++j) acc[i][j] = 0.0f;

  const size_t aoff0 = (M0 + r0) * K_SZ + q0;
  const size_t aoff1 = (M0 + r0 + 64) * K_SZ + q0;
  const size_t boff0 = (size_t)(N0 + r0) * K_SZ + q0;
  const size_t boff1 = (size_t)(N0 + r0 + 64) * K_SZ + q0;

  f32x4 pa0 = ld4t<ISB>(X, aoff0), pa1 = ld4t<ISB>(X, aoff1);
  f32x4 pb0 = ld4t<ISB>(Wm, boff0), pb1 = ld4t<ISB>(Wm, boff1);

  for (int kk = 0; kk < K_SZ; kk += 16) {
    __syncthreads();  // prior compute done -> LDS free
    As[(q0 + 0) * LSTR + r0] = pa0.x; As[(q0 + 1) * LSTR + r0] = pa0.y;
    As[(q0 + 2) * LSTR + r0] = pa0.z; As[(q0 + 3) * LSTR + r0] = pa0.w;
    As[(q0 + 0) * LSTR + r0 + 64] = pa1.x; As[(q0 + 1) * LSTR + r0 + 64] = pa1.y;
    As[(q0 + 2) * LSTR + r0 + 64] = pa1.z; As[(q0 + 3) * LSTR + r0 + 64] = pa1.w;
    Bs[(q0 + 0) * LSTR + r0] = pb0.x; Bs[(q0 + 1) * LSTR + r0] = pb0.y;
    Bs[(q0 + 2) * LSTR + r0] = pb0.z; Bs[(q0 + 3) * LSTR + r0] = pb0.w;
    Bs[(q0 + 0) * LSTR + r0 + 64] = pb1.x; Bs[(q0 + 1) * LSTR + r0 + 64] = pb1.y;
    Bs[(q0 + 2) * LSTR + r0 + 64] = pb1.z; Bs[(q0 + 3) * LSTR + r0 + 64] = pb1.w;
    __syncthreads();  // tile ready
    if (kk + 16 < K_SZ) {  // prefetch next chunk; in flight across compute
      pa0 = ld4t<ISB>(X, aoff0 + kk + 16); pa1 = ld4t<ISB>(X, aoff1 + kk + 16);
      pb0 = ld4t<ISB>(Wm, boff0 + kk + 16); pb1 = ld4t<ISB>(Wm, boff1 + kk + 16);
    }
#pragma unroll
    for (int k = 0; k < 16; ++k) {
      const f32x4 a0 = *reinterpret_cast<const f32x4*>(As + k * LSTR + ty * 4);
      const f32x4 a1 = *reinterpret_cast<const f32x4*>(As + k * LSTR + 64 + ty * 4);
      const f32x4 b0 = *reinterpret_cast<const f32x4*>(Bs + k * LSTR + tx * 4);
      const f32x4 b1 = *reinterpret_cast<const f32x4*>(Bs + k * LSTR + 64 + tx * 4);
      const float av[8] = {a0.x, a0.y, a0.z, a0.w, a1.x, a1.y, a1.z, a1.w};
      const float bv[8] = {b0.x, b0.y, b0.z, b0.w, b1.x, b1.y, b1.z, b1.w};
#pragma unroll
      for (int i = 0; i < 8; ++i)
#pragma unroll
        for (int j = 0; j < 8; ++j) acc[i][j] += av[i] * bv[j];  // contracts to FMA
    }
  }

#pragma unroll
  for (int r = 0; r < 8; ++r) {
    const size_t m = M0 + ((r < 4) ? (ty * 4 + r) : (64 + ty * 4 + (r - 4)));
    float* Cp = C + m * H_SZ + N0;
    f32x4 v0 = {acc[r][0], acc[r][1], acc[r][2], acc[r][3]};
    f32x4 v1 = {acc[r][4], acc[r][5], acc[r][6], acc[r][7]};
    // plain (cached) stores: Wx (134 MB) stays resident in 256 MB L3 for the scan
    *reinterpret_cast<f32x4*>(Cp + tx * 4) = v0;
    *reinterpret_cast<f32x4*>(Cp + 64 + tx * 4) = v1;
  }
}

__global__ __launch_bounds__(256) void sgemm_bt(const void* __restrict__ X,
                                                const void* __restrict__ Wm,
                                                float* __restrict__ C) {
  __shared__ float As[16 * LSTR];  // 8.45 KB
  __shared__ float Bs[16 * LSTR];  // 8.45 KB
  if (detect_bf16(reinterpret_cast<const unsigned int*>(X)))
    gemm_body<true>(X, Wm, C, As, Bs);
  else
    gemm_body<false>(X, Wm, C, As, Bs);
}

// ---------------- LIF scan: producer-consumer over LDS rings -----------------
// 1024 blocks x 512 thr (8 waves); block = (b, 64-h strip), lane = h.
// Superchunk SC=32 t-rows; double-buffered LDS in-ring (Wx rows) and out-ring
// (spike rows). Iteration sc with parity par=sc&1:
//   consumer (wave 0): for j in 0..31: ds_read inb[par][j] -> 8 VALU ->
//                      ds_write outb[par][j]   (LDS-only, ~30 cyc/step)
//   producers (1..7):  global_load superchunk sc+1 rows -> inb[par^1];
//                      ds_read outb[par^1] (sc-1 spikes) -> global_store out.
// One __syncthreads per superchunk; every wave executes the same barrier count.
// Rows strided across producers (r = pw, pw+7, ...). 32 KB LDS -> 4 blocks/CU.
#define SC 32              // t-rows per superchunk
#define NSC (T_SZ / SC)    // 16 superchunks
#define PMAX 5             // max rows per producer per superchunk (ceil 32/7)

template <bool ISB>
__device__ __forceinline__ void scan_body(
    const float* __restrict__ wx, const void* __restrict__ alpha_p,
    const void* __restrict__ beta_p, const void* __restrict__ a_p,
    const void* __restrict__ b_p, const void* __restrict__ u0p,
    const void* __restrict__ w0p, const void* __restrict__ s0p,
    void* __restrict__ out, float* __restrict__ inb, float* __restrict__ outb) {
  const int tid = threadIdx.x;
  const int lane = tid & 63;   // h within strip
  const int wid = tid >> 6;    // 0 = consumer, 1..7 = producers
  const int b = blockIdx.x >> 3;
  const int h = (blockIdx.x & 7) * 64 + lane;

  auto IN = [&](int par, int r) -> float* { return inb + (par * SC + r) * 64; };
  auto OUT = [&](int par, int r) -> float* { return outb + (par * SC + r) * 64; };

  const float* xrow = wx + (size_t)b * T_SZ * H_SZ + h;  // row t: + t*H_SZ
  float* outf = reinterpret_cast<float*>(out);
  unsigned short* outu = reinterpret_cast<unsigned short*>(out);
  const size_t ob0 = (size_t)b * T_SZ * H_SZ + h;

  if (wid == 0) {
    // ---- consumer: recurrence, LDS-only traffic ----
    const float al = fminf(fmaxf(ld1t<ISB>(alpha_p, h), (float)0.8187307530779818),
                           (float)0.9607894391523232);
    const float be = fminf(fmaxf(ld1t<ISB>(beta_p, h), (float)0.9672161004820059),
                           (float)0.9917013044213351);
    const float av = fminf(fmaxf(ld1t<ISB>(a_p, h), -1.0f), 1.0f);
    const float bv = fminf(fmaxf(ld1t<ISB>(b_p, h), 0.0f), 2.0f);
    const float om = __fsub_rn(1.0f, al);
    const int bh = b * H_SZ + h;
    float u = ld1t<ISB>(u0p, bh);
    float w = ld1t<ISB>(w0p, bh);
    float s = ld1t<ISB>(s0p, bh);

    __syncthreads();  // [1] inb[0] ready (matches producers' preamble barrier)
    for (int sc = 0; sc < NSC; ++sc) {
      const int par = sc & 1;
      float nxt = IN(par, 0)[lane];
#pragma unroll
      for (int j = 0; j < SC; ++j) {
        const float cur = nxt;
        if (j + 1 < SC) nxt = IN(par, j + 1)[lane];  // LDS read-ahead
        // numpy left-to-right, each op individually rounded (no FMA contraction)
        w = __fadd_rn(__fadd_rn(__fmul_rn(be, w), __fmul_rn(av, u)), __fmul_rn(bv, s));
        u = __fadd_rn(__fmul_rn(al, __fsub_rn(u, s)), __fmul_rn(om, __fsub_rn(cur, w)));
        s = (u > 1.0f) ? 1.0f : 0.0f;
        OUT(par, j)[lane] = s;
      }
      __syncthreads();  // [2..17] superchunk boundary
    }
  } else {
    // ---- producers: all global memory traffic, 7-way wave parallelism ----
    const int pw = wid - 1;  // 0..6
    float ld[PMAX];
    // preamble: fill inb[0] with superchunk 0
#pragma unroll
    for (int k = 0; k < PMAX; ++k) {
      const int r = pw + 7 * k;
      if (r < SC) ld[k] = xrow[(size_t)r * H_SZ];
    }
#pragma unroll
    for (int k = 0; k < PMAX; ++k) {
      const int r = pw + 7 * k;
      if (r < SC) IN(0, r)[lane] = ld[k];
    }
    __syncthreads();  // [1] inb[0] ready
    for (int sc = 0; sc < NSC; ++sc) {
      const int par = sc & 1;
      // issue loads for superchunk sc+1 first (independent; deep in flight)
      if (sc + 1 < NSC) {
#pragma unroll
        for (int k = 0; k < PMAX; ++k) {
          const int r = pw + 7 * k;
          if (r < SC) ld[k] = xrow[(size_t)((sc + 1) * SC + r) * H_SZ];
        }
      }
      // drain spikes of superchunk sc-1 from outb[par^1] while loads fly
      if (sc > 0) {
#pragma unroll
        for (int k = 0; k < PMAX; ++k) {
          const int r = pw + 7 * k;
          if (r < SC) {
            const float sv = OUT(par ^ 1, r)[lane];
            const size_t o = ob0 + (size_t)((sc - 1) * SC + r) * H_SZ;
            if constexpr (ISB)
              outu[o] = (sv != 0.0f) ? (unsigned short)0x3F80u : (unsigned short)0u;
            else
              outf[o] = sv;
          }
        }
      }
      // commit arrived loads into inb[par^1]
      if (sc + 1 < NSC) {
#pragma unroll
        for (int k = 0; k < PMAX; ++k) {
          const int r = pw + 7 * k;
          if (r < SC) IN(par ^ 1, r)[lane] = ld[k];
        }
      }
      __syncthreads();  // [2..17] superchunk boundary
    }
    // epilogue: drain last superchunk (sc = NSC-1) from outb[(NSC-1)&1]
#pragma unroll
    for (int k = 0; k < PMAX; ++k) {
      const int r = pw + 7 * k;
      if (r < SC) {
        const float sv = OUT((NSC - 1) & 1, r)[lane];
        const size_t o = ob0 + (size_t)((NSC - 1) * SC + r) * H_SZ;
        if constexpr (ISB)
          outu[o] = (sv != 0.0f) ? (unsigned short)0x3F80u : (unsigned short)0u;
        else
          outf[o] = sv;
      }
    }
  }
}

__global__ __launch_bounds__(512) void lif_scan(
    const float* __restrict__ wx, const void* __restrict__ X,
    const void* __restrict__ alpha_p, const void* __restrict__ beta_p,
    const void* __restrict__ a_p, const void* __restrict__ b_p,
    const void* __restrict__ u0p, const void* __restrict__ w0p,
    const void* __restrict__ s0p, void* __restrict__ out) {
  __shared__ float inb[2 * SC * 64];   // 16 KB: Wx row ring
  __shared__ float outb[2 * SC * 64];  // 16 KB: spike row ring
  if (detect_bf16(reinterpret_cast<const unsigned int*>(X)))
    scan_body<true>(wx, alpha_p, beta_p, a_p, b_p, u0p, w0p, s0p, out, inb, outb);
  else
    scan_body<false>(wx, alpha_p, beta_p, a_p, b_p, u0p, w0p, s0p, out, inb, outb);
}

extern "C" void kernel_launch(void* const* d_in, const int* in_sizes, int n_in,
                              void* d_out, int out_size, void* d_ws, size_t ws_size,
                              hipStream_t stream) {
  const void* X = d_in[0];   // x [B,T,I]
  const void* Wm = d_in[1];  // W [H,I]
  float* ws = reinterpret_cast<float*>(d_ws);  // Wx fp32 [B,T,H]

  sgemm_bt<<<dim3((M_SZ / 128) * (H_SZ / 128)), dim3(256), 0, stream>>>(X, Wm, ws);

  lif_scan<<<dim3(B_SZ * 8), dim3(512), 0, stream>>>(
      ws, X, d_in[2], d_in[3], d_in[4], d_in[5], d_in[6], d_in[7], d_in[8], d_out);
}